// Round 2
// baseline (5812.085 us; speedup 1.0000x reference)
//
#include <hip/hip_runtime.h>
#include <math.h>

#define SS 512
#define BB 32
#define HH 256
#define G4 1024
#define TT 11
#define NEGV (-1000.0f)

typedef unsigned long long ull;

// ---------------- workspace layout (bytes) ----------------
static const size_t OFF_XEH   = 0;                          // 8,388,608  : xe_hi [16384][256] bf16
static const size_t OFF_XEL   = 8388608ull;                 // 8,388,608  : xe_lo
static const size_t OFF_XS    = 16777216ull;                // 134,217,728: xs [2][S][B][1024] f32
static const size_t OFF_H0    = OFF_XS + 134217728ull;      // 33,554,432 : h0 [B*S][512] f32
static const size_t OFF_H1    = OFF_H0 + 33554432ull;       // 33,554,432 : h1 f32 (also h0_hi/h0_lo bf16 before scan1)
static const size_t OFF_FEATS = OFF_H1 + 33554432ull;       // 720,896    : feats [B][S][11]
static const size_t OFF_HGRP  = OFF_FEATS + 720896ull;      // 524,288    : fast + slow mailboxes [2][2][32][256] u64 each
static const size_t OFF_W0H   = OFF_HGRP + 1048576ull;      // 1,048,576  : wih0 hi [2][1024][256] bf16
static const size_t OFF_W0L   = OFF_W0H + 1048576ull;       // 1,048,576
static const size_t OFF_W1H   = OFF_W0L + 1048576ull;       // 2,097,152  : wih1 hi [2][1024][512] bf16
static const size_t OFF_W1L   = OFF_W1H + 2097152ull;       // 2,097,152
// total ~226 MB

typedef __attribute__((ext_vector_type(8))) short short8;
typedef __attribute__((ext_vector_type(4))) float f32x4;

// fast transcendentals (1-2 ulp; outputs compared in bf16 w/ large threshold)
__device__ __forceinline__ float fsig(float x) {
  return __builtin_amdgcn_rcpf(1.f + __expf(-x));
}
__device__ __forceinline__ float ftanh(float x) {
  return 1.f - 2.f * __builtin_amdgcn_rcpf(__expf(2.f * x) + 1.f);
}

// ---------------- bf16 hi/lo split helpers ----------------
__device__ __forceinline__ unsigned short bfh(float x) {
  unsigned u = __float_as_uint(x);
  unsigned r = u + 0x7fffu + ((u >> 16) & 1u);   // RNE to bf16 (finite inputs)
  return (unsigned short)(r >> 16);
}
__device__ __forceinline__ void split1(float x, unsigned short& h, unsigned short& l) {
  h = bfh(x);
  float hf = __uint_as_float(((unsigned)h) << 16);
  l = bfh(x - hf);
}

// ---------------- fast-mailbox primitives (same-XCD L2 relay) ----------------
// sc0 load: bypass L1, served by the XCD's L2 (old "glc"). Producer's plain
// global_store writes through to the same L2 -> same-XCD consumers see it at
// L2 latency (~200-300cy) instead of LLC atomic latency (~900cy).
__device__ __forceinline__ void fast_load4(const ull* a0, const ull* a1,
                                           const ull* a2, const ull* a3,
                                           ull& r0, ull& r1, ull& r2, ull& r3) {
  asm volatile(
      "global_load_dwordx2 %0, %4, off sc0\n\t"
      "global_load_dwordx2 %1, %5, off sc0\n\t"
      "global_load_dwordx2 %2, %6, off sc0\n\t"
      "global_load_dwordx2 %3, %7, off sc0\n\t"
      "s_waitcnt vmcnt(0)"
      : "=&v"(r0), "=&v"(r1), "=&v"(r2), "=&v"(r3)
      : "v"(a0), "v"(a1), "v"(a2), "v"(a3)
      : "memory");
}
__device__ __forceinline__ void fast_store(ull* a, ull v) {
  asm volatile("global_store_dwordx2 %0, %1, off" :: "v"(a), "v"(v) : "memory");
}

// ---------------- embedding gather + split ----------------
__global__ void emb_kernel(const int* __restrict__ x, const float4* __restrict__ emb,
                           ushort4* __restrict__ xeh, ushort4* __restrict__ xel) {
  int idx = blockIdx.x * 256 + threadIdx.x;    // over B*S*64 float4-chunks
  int bs  = idx >> 6;
  int kq  = idx & 63;
  float4 v = emb[(size_t)x[bs] * 64 + kq];
  ushort4 h, l;
  split1(v.x, h.x, l.x); split1(v.y, h.y, l.y);
  split1(v.z, h.z, l.z); split1(v.w, h.w, l.w);
  xeh[idx] = h; xel[idx] = l;
}

// ---------------- generic f32 -> bf16 hi/lo split ----------------
__global__ void split_kernel(const float4* __restrict__ in, ushort4* __restrict__ oh,
                             ushort4* __restrict__ ol, int n4) {
  int i = blockIdx.x * 256 + threadIdx.x;
  if (i < n4) {
    float4 v = in[i];
    ushort4 h, l;
    split1(v.x, h.x, l.x); split1(v.y, h.y, l.y);
    split1(v.z, h.z, l.z); split1(v.w, h.w, l.w);
    oh[i] = h; ol[i] = l;
  }
}

// ---------------- input projection GEMM via split-bf16 MFMA ----------------
// (unchanged -- verified)
template<int K>
__global__ __launch_bounds__(256, 2)
void proj_mfma(const unsigned short* __restrict__ Ah_g, const unsigned short* __restrict__ Al_g,
               const unsigned short* __restrict__ Wh_g, const unsigned short* __restrict__ Wl_g,
               const float* __restrict__ bf, const float* __restrict__ bb,
               float* __restrict__ xs) {
  int tid = threadIdx.x;
  int bm  = blockIdx.x * 64;
  int bn  = blockIdx.y * 128;
  int dir = blockIdx.z;
  const unsigned short* Wh = Wh_g + (size_t)dir * 1024 * K;
  const unsigned short* Wl = Wl_g + (size_t)dir * 1024 * K;
  const float* bias = dir ? bb : bf;
  float* out = xs + (size_t)dir * (SS * BB * G4);

  __shared__ unsigned short AhS[64][40], AlS[64][40];
  __shared__ unsigned short BhS[128][40], BlS[128][40];

  int w = tid >> 6, lane = tid & 63;
  int wm = w >> 1, wn = w & 1;
  int fr = lane & 15, q8 = (lane >> 4) * 8;
  int ra = tid >> 2;
  int ck = (tid & 3) * 8;

  f32x4 acc[2][4];
  #pragma unroll
  for (int mt = 0; mt < 2; mt++)
    #pragma unroll
    for (int nt = 0; nt < 4; nt++) acc[mt][nt] = 0;

  for (int k0 = 0; k0 < K; k0 += 32) {
    __syncthreads();
    *(uint4*)&AhS[ra][ck] = *(const uint4*)(Ah_g + (size_t)(bm + ra) * K + k0 + ck);
    *(uint4*)&AlS[ra][ck] = *(const uint4*)(Al_g + (size_t)(bm + ra) * K + k0 + ck);
    *(uint4*)&BhS[ra][ck]      = *(const uint4*)(Wh + (size_t)(bn + ra) * K + k0 + ck);
    *(uint4*)&BhS[ra + 64][ck] = *(const uint4*)(Wh + (size_t)(bn + ra + 64) * K + k0 + ck);
    *(uint4*)&BlS[ra][ck]      = *(const uint4*)(Wl + (size_t)(bn + ra) * K + k0 + ck);
    *(uint4*)&BlS[ra + 64][ck] = *(const uint4*)(Wl + (size_t)(bn + ra + 64) * K + k0 + ck);
    __syncthreads();

    short8 ah[2], al[2], bh[4], bl[4];
    #pragma unroll
    for (int mt = 0; mt < 2; mt++) {
      ah[mt] = *(const short8*)&AhS[wm * 32 + mt * 16 + fr][q8];
      al[mt] = *(const short8*)&AlS[wm * 32 + mt * 16 + fr][q8];
    }
    #pragma unroll
    for (int nt = 0; nt < 4; nt++) {
      bh[nt] = *(const short8*)&BhS[wn * 64 + nt * 16 + fr][q8];
      bl[nt] = *(const short8*)&BlS[wn * 64 + nt * 16 + fr][q8];
    }
    #pragma unroll
    for (int mt = 0; mt < 2; mt++)
      #pragma unroll
      for (int nt = 0; nt < 4; nt++) {
        acc[mt][nt] = __builtin_amdgcn_mfma_f32_16x16x32_bf16(ah[mt], bh[nt], acc[mt][nt], 0, 0, 0);
        acc[mt][nt] = __builtin_amdgcn_mfma_f32_16x16x32_bf16(ah[mt], bl[nt], acc[mt][nt], 0, 0, 0);
        acc[mt][nt] = __builtin_amdgcn_mfma_f32_16x16x32_bf16(al[mt], bh[nt], acc[mt][nt], 0, 0, 0);
        acc[mt][nt] = __builtin_amdgcn_mfma_f32_16x16x32_bf16(al[mt], bl[nt], acc[mt][nt], 0, 0, 0);
      }
  }

  #pragma unroll
  for (int mt = 0; mt < 2; mt++)
    #pragma unroll
    for (int nt = 0; nt < 4; nt++) {
      int n  = bn + wn * 64 + nt * 16 + fr;
      float bv = bias[n];
      int mbase = bm + wm * 32 + mt * 16 + (lane >> 4) * 4;
      #pragma unroll
      for (int r = 0; r < 4; r++) {
        int mm = mbase + r;
        int b_ = mm >> 9;
        int s_ = mm & 511;
        out[(size_t)(s_ * BB + b_) * G4 + n] = acc[mt][nt][r] + bv;
      }
    }
}

// ---------------- recurrent scan (R10: same-XCD L2 relay, barrier-free) ----------------
// Grid: 256 1D blocks x 256 threads. bid = cg*64 + chain, chain = b*2+dir.
// All 4 cg blocks of a chain have bid === chain (mod 8) -> same XCD (empirical
// round-robin dispatch) -> fast mailbox relays meet in the XCD's L2.
// Each WAVE is autonomous (no barriers): 64 lanes = 64 full-K rows
// (16 cells x 4 gates), 256 weight floats in VGPRs. Wave polls all 256 cells
// itself (4 u64/lane), stages to wave-private LDS, lgkmcnt(0), packed-FMA
// matvec, 4-shfl gate gather, 16 update lanes store tagged h.
// Sync protocol: tagged u64 {tag=s+1 | h bits} per cell, parity double-buffer,
// memset-0 init (tag 0 == h(0)=0). Fast path: plain store + sc0 load (XCD L2).
// Slow path (correctness guarantee, placement-independent): agent-scope atomic
// store to a SEPARATE mailbox, probed every 16 failed fast iterations.
// Capture-before-store invariant: a wave stores tag s+1 only after capturing
// all tag-s values in registers/LDS; tag-s slots are overwritten (tag s+2)
// only after every wave stored s+1, i.e. after every wave captured s. Safe.
__global__ __launch_bounds__(256, 1)
void scan_kernel(const float* __restrict__ xs,      // [2][S][B][1024]
                 const float* __restrict__ whhf, const float* __restrict__ whhb,
                 ull* __restrict__ fastM,           // [2][2][32][256] u64
                 ull* __restrict__ slowM,           // [2][2][32][256] u64
                 float* __restrict__ hout)          // [B*S][512]
{
  int tid  = threadIdx.x;
  int w    = tid >> 6;          // wave 0..3
  int lane = tid & 63;
  int bid  = blockIdx.x;
  int chain = bid & 63;
  int cg    = bid >> 6;         // cell group 0..3 (64 cells)
  int b     = chain >> 1;
  int dir   = chain & 1;
  const float* xsd = xs + (size_t)dir * (SS * BB * G4);
  const float* whh = dir ? whhb : whhf;

  int g    = lane >> 4;         // gate 0..3 (i,f,g,o)
  int cidx = lane & 15;
  int cell = cg * 64 + w * 16 + cidx;
  int grow = g * 256 + cell;    // whh row (full K)

  __shared__ float hsh[4][2][256];   // [wave][parity][cell] -- wave-private

  // weights: 1 full row = 256 floats = 64 float4 in VGPRs
  f32x4 wreg[64];
  {
    const float* wp = whh + (size_t)grow * 256;
    #pragma unroll
    for (int j = 0; j < 64; j++) wreg[j] = *(const f32x4*)(wp + 4 * j);
  }

  // mailbox bases: index ((dir*2+p)*32 + b)*256 + col
  size_t mb0 = ((size_t)(dir * 2 + 0) * 32 + b) * 256;
  size_t mb1 = ((size_t)(dir * 2 + 1) * 32 + b) * 256;

  bool ul = (lane < 16);        // update lane: owns cell `cell` (g==0 rows)
  float cst = 0.f;
  float xfA[4], xfB[4];         // x-projection, depth-2 prefetch
  if (ul) {
    int t0 = dir ? (SS - 1) : 0;
    int t1 = dir ? (SS - 2) : 1;
    const float* xp0 = xsd + (size_t)(t0 * BB + b) * G4 + cell;
    const float* xp1 = xsd + (size_t)(t1 * BB + b) * G4 + cell;
    #pragma unroll
    for (int i = 0; i < 4; i++) { xfA[i] = xp0[i * 256]; xfB[i] = xp1[i * 256]; }
  }

  for (int s = 0; s < SS; ++s) {
    int p = s & 1;
    size_t mb = p ? mb1 : mb0;
    const ull* fa = fastM + mb;
    const ull* sa = slowM + mb;
    unsigned st = (unsigned)s;
    ull r0, r1, r2, r3;

    for (;;) {
      bool got = false;
      for (int it = 0; it < 16; ++it) {
        fast_load4(fa + lane, fa + 64 + lane, fa + 128 + lane, fa + 192 + lane,
                   r0, r1, r2, r3);
        unsigned m = (((unsigned)(r0 >> 32)) ^ st) | (((unsigned)(r1 >> 32)) ^ st)
                   | (((unsigned)(r2 >> 32)) ^ st) | (((unsigned)(r3 >> 32)) ^ st);
        if (__all(m == 0u)) { got = true; break; }
      }
      if (got) break;
      // slow probe (LLC, placement-independent guarantee)
      ull q0 = __hip_atomic_load(sa + lane,        __ATOMIC_RELAXED, __HIP_MEMORY_SCOPE_AGENT);
      ull q1 = __hip_atomic_load(sa + 64 + lane,   __ATOMIC_RELAXED, __HIP_MEMORY_SCOPE_AGENT);
      ull q2 = __hip_atomic_load(sa + 128 + lane,  __ATOMIC_RELAXED, __HIP_MEMORY_SCOPE_AGENT);
      ull q3 = __hip_atomic_load(sa + 192 + lane,  __ATOMIC_RELAXED, __HIP_MEMORY_SCOPE_AGENT);
      unsigned m = (((unsigned)(q0 >> 32)) ^ st) | (((unsigned)(q1 >> 32)) ^ st)
                 | (((unsigned)(q2 >> 32)) ^ st) | (((unsigned)(q3 >> 32)) ^ st);
      if (__all(m == 0u)) { r0 = q0; r1 = q1; r2 = q2; r3 = q3; break; }
    }

    // stage h_s into wave-private LDS (stride-1 across lanes: conflict-free)
    hsh[w][p][lane]       = __uint_as_float((unsigned)r0);
    hsh[w][p][64 + lane]  = __uint_as_float((unsigned)r1);
    hsh[w][p][128 + lane] = __uint_as_float((unsigned)r2);
    hsh[w][p][192 + lane] = __uint_as_float((unsigned)r3);

    // prefetch x-projection for step s+2 (drained harmlessly at next poll)
    float xfN[4] = {0.f, 0.f, 0.f, 0.f};
    if (ul && s + 2 < SS) {
      int tn = dir ? (SS - 3 - s) : (s + 2);
      const float* xp = xsd + (size_t)(tn * BB + b) * G4 + cell;
      #pragma unroll
      for (int i = 0; i < 4; i++) xfN[i] = xp[i * 256];
    }

    asm volatile("s_waitcnt lgkmcnt(0)" ::: "memory");  // own-wave LDS writes done

    // matvec: full 256-k dot, packed f32 FMA; h reads wave-uniform (broadcast)
    f32x4 acc4 = {0.f, 0.f, 0.f, 0.f};
    const float* hb = &hsh[w][p][0];
    #pragma unroll
    for (int j = 0; j < 64; j++) {
      f32x4 hv = *(const f32x4*)(hb + 4 * j);
      acc4 = acc4 + wreg[j] * hv;
    }
    float accv = (acc4.x + acc4.y) + (acc4.z + acc4.w);

    // gather the 4 gate values of this lane's cell (rows g2*16 + cidx)
    float gv[4];
    #pragma unroll
    for (int g2 = 0; g2 < 4; ++g2) gv[g2] = __shfl(accv, g2 * 16 + cidx, 64);

    if (ul) {
      float ig = fsig(gv[0] + xfA[0]);
      float fg = fsig(gv[1] + xfA[1]);
      float gt = ftanh(gv[2] + xfA[2]);
      float og = fsig(gv[3] + xfA[3]);
      cst = fg * cst + ig * gt;
      float hv = og * ftanh(cst);
      ull tagw = ((ull)(unsigned)(s + 1) << 32) | (ull)__float_as_uint(hv);
      size_t mbn = ((s + 1) & 1) ? mb1 : mb0;
      fast_store(fastM + mbn + cell, tagw);
      __hip_atomic_store(slowM + mbn + cell, tagw,
                         __ATOMIC_RELAXED, __HIP_MEMORY_SCOPE_AGENT);
      int tcur = dir ? (SS - 1 - s) : s;
      hout[((size_t)(b * SS + tcur)) * 512 + dir * 256 + cell] = hv;
    }

    #pragma unroll
    for (int i = 0; i < 4; i++) { xfA[i] = xfB[i]; xfB[i] = xfN[i]; }
  }
}

// ---------------- emission features ----------------
__global__ void feats_kernel(const float* __restrict__ h1, const float* __restrict__ wout,
                             const float* __restrict__ bout, float* __restrict__ feats) {
  int bs = blockIdx.x;
  int lane = threadIdx.x;
  const float* hp = h1 + (size_t)bs * 512;
  float hv[8];
  #pragma unroll
  for (int i = 0; i < 8; i++) hv[i] = hp[lane + i * 64];
  #pragma unroll
  for (int t = 0; t < TT; t++) {
    const float* wp = wout + t * 512;
    float p = 0.f;
    #pragma unroll
    for (int i = 0; i < 8; i++) p += hv[i] * wp[lane + i * 64];
    #pragma unroll
    for (int off = 32; off >= 1; off >>= 1) p += __shfl_down(p, off, 64);
    if (lane == 0) feats[(size_t)bs * TT + t] = p + bout[t];
  }
}

// ---------------- Viterbi decode ----------------
__global__ void viterbi_kernel(const float* __restrict__ feats, const float* __restrict__ trans,
                               float* __restrict__ out) {
  int b = blockIdx.x;
  int lane = threadIdx.x;
  __shared__ float tr[121];
  __shared__ float fch[32 * TT];
  __shared__ unsigned char bp[SS][12];
  __shared__ unsigned char path[SS];
  for (int i = lane; i < 121; i += 64) tr[i] = trans[i];
  __syncthreads();
  int ln = lane < TT ? lane : (TT - 1);
  float trr[TT];
  #pragma unroll
  for (int p = 0; p < TT; p++) trr[p] = tr[ln * TT + p];
  float fv = (lane == 9) ? 0.f : NEGV;   // START = 9
  const float* fb = feats + (size_t)b * SS * TT;

  for (int s = 0; s < SS; s++) {
    if ((s & 31) == 0) {
      __syncthreads();
      for (int i = lane; i < 32 * TT; i += 64) fch[i] = fb[s * TT + i];
      __syncthreads();
    }
    float best = -3.0e38f; int arg = 0;
    #pragma unroll
    for (int p = 0; p < TT; p++) {
      float v = __shfl(fv, p, 64) + trr[p];
      if (v > best) { best = v; arg = p; }   // strict > keeps FIRST max (numpy argmax)
    }
    if (lane < TT) bp[s][lane] = (unsigned char)arg;
    fv = best + fch[(s & 31) * TT + ln];
  }
  float term = fv + tr[10 * TT + ln];        // STOP = 10
  float best = -3.0e38f; int arg = 0;
  #pragma unroll
  for (int p = 0; p < TT; p++) {
    float v = __shfl(term, p, 64);
    if (v > best) { best = v; arg = p; }
  }
  __syncthreads();
  if (lane == 0) {
    out[b] = best;
    int tg = arg;
    path[SS - 1] = (unsigned char)tg;
    for (int s = SS - 1; s >= 1; s--) {
      tg = bp[s][tg];
      path[s - 1] = (unsigned char)tg;
    }
  }
  __syncthreads();
  for (int i = lane; i < SS; i += 64) out[32 + b * SS + i] = (float)path[i];
}

// ---------------- launcher ----------------
extern "C" void kernel_launch(void* const* d_in, const int* in_sizes, int n_in,
                              void* d_out, int out_size, void* d_ws, size_t ws_size,
                              hipStream_t stream) {
  const int*   x     = (const int*)d_in[0];
  const float* emb   = (const float*)d_in[2];
  const float* wih0f = (const float*)d_in[3];
  const float* whh0f = (const float*)d_in[4];
  const float* b0f   = (const float*)d_in[5];
  const float* wih0b = (const float*)d_in[6];
  const float* whh0b = (const float*)d_in[7];
  const float* b0b   = (const float*)d_in[8];
  const float* wih1f = (const float*)d_in[9];
  const float* whh1f = (const float*)d_in[10];
  const float* b1f   = (const float*)d_in[11];
  const float* wih1b = (const float*)d_in[12];
  const float* whh1b = (const float*)d_in[13];
  const float* b1b   = (const float*)d_in[14];
  const float* wout  = (const float*)d_in[15];
  const float* bout  = (const float*)d_in[16];
  const float* trans = (const float*)d_in[17];

  char* ws = (char*)d_ws;
  unsigned short* xeh = (unsigned short*)(ws + OFF_XEH);
  unsigned short* xel = (unsigned short*)(ws + OFF_XEL);
  float* xs    = (float*)(ws + OFF_XS);
  float* h0    = (float*)(ws + OFF_H0);
  float* h1    = (float*)(ws + OFF_H1);
  unsigned short* h0h = (unsigned short*)(ws + OFF_H1);               // overlay (dead until scan1)
  unsigned short* h0l = (unsigned short*)(ws + OFF_H1 + 16777216ull);
  float* feats = (float*)(ws + OFF_FEATS);
  ull* fastM = (ull*)(ws + OFF_HGRP);
  ull* slowM = (ull*)(ws + OFF_HGRP + 262144ull);
  unsigned short* w0h = (unsigned short*)(ws + OFF_W0H);
  unsigned short* w0l = (unsigned short*)(ws + OFF_W0L);
  unsigned short* w1h = (unsigned short*)(ws + OFF_W1H);
  unsigned short* w1l = (unsigned short*)(ws + OFF_W1L);
  float* outp  = (float*)d_out;

  // embedding gather + hi/lo split
  emb_kernel<<<4096, 256, 0, stream>>>(x, (const float4*)emb, (ushort4*)xeh, (ushort4*)xel);
  // weight splits: wih0 [2][1024][256], wih1 [2][1024][512]
  split_kernel<<<256, 256, 0, stream>>>((const float4*)wih0f, (ushort4*)w0h, (ushort4*)w0l, 65536);
  split_kernel<<<256, 256, 0, stream>>>((const float4*)wih0b, (ushort4*)(w0h + 262144),
                                        (ushort4*)(w0l + 262144), 65536);
  split_kernel<<<512, 256, 0, stream>>>((const float4*)wih1f, (ushort4*)w1h, (ushort4*)w1l, 131072);
  split_kernel<<<512, 256, 0, stream>>>((const float4*)wih1b, (ushort4*)(w1h + 524288),
                                        (ushort4*)(w1l + 524288), 131072);

  proj_mfma<256><<<dim3(256, 8, 2), 256, 0, stream>>>(xeh, xel, w0h, w0l, b0f, b0b, xs);
  hipMemsetAsync(fastM, 0, 524288, stream);   // tag 0 == initial h(0) = 0, both mailboxes
  scan_kernel<<<256, 256, 0, stream>>>(xs, whh0f, whh0b, fastM, slowM, h0);

  split_kernel<<<8192, 256, 0, stream>>>((const float4*)h0, (ushort4*)h0h, (ushort4*)h0l, 2097152);
  proj_mfma<512><<<dim3(256, 8, 2), 256, 0, stream>>>(h0h, h0l, w1h, w1l, b1f, b1b, xs);
  hipMemsetAsync(fastM, 0, 524288, stream);
  scan_kernel<<<256, 256, 0, stream>>>(xs, whh1f, whh1b, fastM, slowM, h1);

  feats_kernel<<<BB * SS, 64, 0, stream>>>(h1, wout, bout, feats);
  viterbi_kernel<<<BB, 64, 0, stream>>>(feats, trans, outp);
}

// Round 3
// 3543.896 us; speedup vs baseline: 1.6400x; 1.6400x over previous
//
#include <hip/hip_runtime.h>
#include <math.h>

#define SS 512
#define BB 32
#define HH 256
#define G4 1024
#define TT 11
#define NEGV (-1000.0f)

typedef unsigned long long ull;

// ---------------- workspace layout (bytes) ----------------
static const size_t OFF_XEH   = 0;                          // 8,388,608  : xe_hi [16384][256] bf16
static const size_t OFF_XEL   = 8388608ull;                 // 8,388,608  : xe_lo
static const size_t OFF_XS    = 16777216ull;                // 134,217,728: xs [2][S][B][1024] f32
static const size_t OFF_H0    = OFF_XS + 134217728ull;      // 33,554,432 : h0 [B*S][512] f32
static const size_t OFF_H1    = OFF_H0 + 33554432ull;       // 33,554,432 : h1 f32 (also h0_hi/h0_lo bf16 before scan1)
static const size_t OFF_FEATS = OFF_H1 + 33554432ull;       // 720,896    : feats [B][S][11]
static const size_t OFF_HGRP  = OFF_FEATS + 720896ull;      // 262,144    : tagged h mailbox [2][2][32][256] u64
static const size_t OFF_W0H   = OFF_HGRP + 1048576ull;      // 1,048,576  : wih0 hi [2][1024][256] bf16
static const size_t OFF_W0L   = OFF_W0H + 1048576ull;       // 1,048,576
static const size_t OFF_W1H   = OFF_W0L + 1048576ull;       // 2,097,152  : wih1 hi [2][1024][512] bf16
static const size_t OFF_W1L   = OFF_W1H + 2097152ull;       // 2,097,152
// total ~226 MB

typedef __attribute__((ext_vector_type(8))) short short8;
typedef __attribute__((ext_vector_type(4))) float f32x4;

// fast transcendentals (1-2 ulp; outputs compared in bf16 w/ large threshold)
__device__ __forceinline__ float fsig(float x) {
  return __builtin_amdgcn_rcpf(1.f + __expf(-x));
}
__device__ __forceinline__ float ftanh(float x) {
  return 1.f - 2.f * __builtin_amdgcn_rcpf(__expf(2.f * x) + 1.f);
}

// ---------------- bf16 hi/lo split helpers ----------------
__device__ __forceinline__ unsigned short bfh(float x) {
  unsigned u = __float_as_uint(x);
  unsigned r = u + 0x7fffu + ((u >> 16) & 1u);   // RNE to bf16 (finite inputs)
  return (unsigned short)(r >> 16);
}
__device__ __forceinline__ void split1(float x, unsigned short& h, unsigned short& l) {
  h = bfh(x);
  float hf = __uint_as_float(((unsigned)h) << 16);
  l = bfh(x - hf);
}

// ---------------- embedding gather + split ----------------
__global__ void emb_kernel(const int* __restrict__ x, const float4* __restrict__ emb,
                           ushort4* __restrict__ xeh, ushort4* __restrict__ xel) {
  int idx = blockIdx.x * 256 + threadIdx.x;    // over B*S*64 float4-chunks
  int bs  = idx >> 6;
  int kq  = idx & 63;
  float4 v = emb[(size_t)x[bs] * 64 + kq];
  ushort4 h, l;
  split1(v.x, h.x, l.x); split1(v.y, h.y, l.y);
  split1(v.z, h.z, l.z); split1(v.w, h.w, l.w);
  xeh[idx] = h; xel[idx] = l;
}

// ---------------- generic f32 -> bf16 hi/lo split ----------------
__global__ void split_kernel(const float4* __restrict__ in, ushort4* __restrict__ oh,
                             ushort4* __restrict__ ol, int n4) {
  int i = blockIdx.x * 256 + threadIdx.x;
  if (i < n4) {
    float4 v = in[i];
    ushort4 h, l;
    split1(v.x, h.x, l.x); split1(v.y, h.y, l.y);
    split1(v.z, h.z, l.z); split1(v.w, h.w, l.w);
    oh[i] = h; ol[i] = l;
  }
}

// ---------------- input projection GEMM via split-bf16 MFMA ----------------
// (unchanged -- verified)
template<int K>
__global__ __launch_bounds__(256, 2)
void proj_mfma(const unsigned short* __restrict__ Ah_g, const unsigned short* __restrict__ Al_g,
               const unsigned short* __restrict__ Wh_g, const unsigned short* __restrict__ Wl_g,
               const float* __restrict__ bf, const float* __restrict__ bb,
               float* __restrict__ xs) {
  int tid = threadIdx.x;
  int bm  = blockIdx.x * 64;
  int bn  = blockIdx.y * 128;
  int dir = blockIdx.z;
  const unsigned short* Wh = Wh_g + (size_t)dir * 1024 * K;
  const unsigned short* Wl = Wl_g + (size_t)dir * 1024 * K;
  const float* bias = dir ? bb : bf;
  float* out = xs + (size_t)dir * (SS * BB * G4);

  __shared__ unsigned short AhS[64][40], AlS[64][40];
  __shared__ unsigned short BhS[128][40], BlS[128][40];

  int w = tid >> 6, lane = tid & 63;
  int wm = w >> 1, wn = w & 1;
  int fr = lane & 15, q8 = (lane >> 4) * 8;
  int ra = tid >> 2;
  int ck = (tid & 3) * 8;

  f32x4 acc[2][4];
  #pragma unroll
  for (int mt = 0; mt < 2; mt++)
    #pragma unroll
    for (int nt = 0; nt < 4; nt++) acc[mt][nt] = 0;

  for (int k0 = 0; k0 < K; k0 += 32) {
    __syncthreads();
    *(uint4*)&AhS[ra][ck] = *(const uint4*)(Ah_g + (size_t)(bm + ra) * K + k0 + ck);
    *(uint4*)&AlS[ra][ck] = *(const uint4*)(Al_g + (size_t)(bm + ra) * K + k0 + ck);
    *(uint4*)&BhS[ra][ck]      = *(const uint4*)(Wh + (size_t)(bn + ra) * K + k0 + ck);
    *(uint4*)&BhS[ra + 64][ck] = *(const uint4*)(Wh + (size_t)(bn + ra + 64) * K + k0 + ck);
    *(uint4*)&BlS[ra][ck]      = *(const uint4*)(Wl + (size_t)(bn + ra) * K + k0 + ck);
    *(uint4*)&BlS[ra + 64][ck] = *(const uint4*)(Wl + (size_t)(bn + ra + 64) * K + k0 + ck);
    __syncthreads();

    short8 ah[2], al[2], bh[4], bl[4];
    #pragma unroll
    for (int mt = 0; mt < 2; mt++) {
      ah[mt] = *(const short8*)&AhS[wm * 32 + mt * 16 + fr][q8];
      al[mt] = *(const short8*)&AlS[wm * 32 + mt * 16 + fr][q8];
    }
    #pragma unroll
    for (int nt = 0; nt < 4; nt++) {
      bh[nt] = *(const short8*)&BhS[wn * 64 + nt * 16 + fr][q8];
      bl[nt] = *(const short8*)&BlS[wn * 64 + nt * 16 + fr][q8];
    }
    #pragma unroll
    for (int mt = 0; mt < 2; mt++)
      #pragma unroll
      for (int nt = 0; nt < 4; nt++) {
        acc[mt][nt] = __builtin_amdgcn_mfma_f32_16x16x32_bf16(ah[mt], bh[nt], acc[mt][nt], 0, 0, 0);
        acc[mt][nt] = __builtin_amdgcn_mfma_f32_16x16x32_bf16(ah[mt], bl[nt], acc[mt][nt], 0, 0, 0);
        acc[mt][nt] = __builtin_amdgcn_mfma_f32_16x16x32_bf16(al[mt], bh[nt], acc[mt][nt], 0, 0, 0);
        acc[mt][nt] = __builtin_amdgcn_mfma_f32_16x16x32_bf16(al[mt], bl[nt], acc[mt][nt], 0, 0, 0);
      }
  }

  #pragma unroll
  for (int mt = 0; mt < 2; mt++)
    #pragma unroll
    for (int nt = 0; nt < 4; nt++) {
      int n  = bn + wn * 64 + nt * 16 + fr;
      float bv = bias[n];
      int mbase = bm + wm * 32 + mt * 16 + (lane >> 4) * 4;
      #pragma unroll
      for (int r = 0; r < 4; r++) {
        int mm = mbase + r;
        int b_ = mm >> 9;
        int s_ = mm & 511;
        out[(size_t)(s_ * BB + b_) * G4 + n] = acc[mt][nt][r] + bv;
      }
    }
}

// ---------------- recurrent scan (R11: wave-autonomous, agent-atomic relay) ----------------
// R10's barrier-free structure + R9's PROVEN transport (agent-scope tagged
// atomics, single mailbox). The R10 fast/slow dual path is deleted: its sc0
// fast mailbox never became visible and each step burned 16 wasted load
// latencies before probing the real one.
// Grid: 256 1D blocks x 256 threads; bid = cg*64 + chain, chain = b*2+dir.
// Each WAVE is autonomous (no barriers): 64 lanes = 64 full-K rows
// (16 cells x 4 gates), 256 weight floats in VGPRs/AGPRs. Wave polls all 256
// cells itself (4 u64/lane), stages to wave-private LDS, lgkmcnt(0),
// packed-FMA matvec, 4-shfl gate gather, 16 update lanes store tagged h.
// Sync protocol (verified R6/R9/R10): tagged u64 {tag=s+1 | h bits} per cell,
// parity double-buffer, memset-0 init (tag 0 == h(0)=0).
// Deadlock/overwrite safety: every wave owns 16 cells, so no wave can store
// tag s+1 (overwriting the tag s-1 parity slot) until ALL waves produced tag
// s, i.e. all waves passed the s-1 poll. Capture-before-overwrite holds.
__global__ __launch_bounds__(256, 1)
void scan_kernel(const float* __restrict__ xs,      // [2][S][B][1024]
                 const float* __restrict__ whhf, const float* __restrict__ whhb,
                 ull* __restrict__ hmb,             // [2][2][32][256] u64 mailbox
                 float* __restrict__ hout)          // [B*S][512]
{
  int tid  = threadIdx.x;
  int w    = tid >> 6;          // wave 0..3
  int lane = tid & 63;
  int bid  = blockIdx.x;
  int chain = bid & 63;
  int cg    = bid >> 6;         // cell group 0..3 (64 cells)
  int b     = chain >> 1;
  int dir   = chain & 1;
  const float* xsd = xs + (size_t)dir * (SS * BB * G4);
  const float* whh = dir ? whhb : whhf;

  int g    = lane >> 4;         // gate 0..3 (i,f,g,o)
  int cidx = lane & 15;
  int cell = cg * 64 + w * 16 + cidx;
  int grow = g * 256 + cell;    // whh row (full K)

  __shared__ float hsh[4][2][256];   // [wave][parity][cell] -- wave-private

  // weights: 1 full row = 256 floats = 64 float4 in VGPRs/AGPRs (unified file)
  f32x4 wreg[64];
  {
    const float* wp = whh + (size_t)grow * 256;
    #pragma unroll
    for (int j = 0; j < 64; j++) wreg[j] = *(const f32x4*)(wp + 4 * j);
  }

  // mailbox bases: index ((dir*2+p)*32 + b)*256 + col
  size_t mb0 = ((size_t)(dir * 2 + 0) * 32 + b) * 256;
  size_t mb1 = ((size_t)(dir * 2 + 1) * 32 + b) * 256;

  bool ul = (lane < 16);        // update lane: owns cell `cell` (g==0 rows)
  float cst = 0.f;
  float xfA[4], xfB[4];         // x-projection, depth-2 prefetch
  if (ul) {
    int t0 = dir ? (SS - 1) : 0;
    int t1 = dir ? (SS - 2) : 1;
    const float* xp0 = xsd + (size_t)(t0 * BB + b) * G4 + cell;
    const float* xp1 = xsd + (size_t)(t1 * BB + b) * G4 + cell;
    #pragma unroll
    for (int i = 0; i < 4; i++) { xfA[i] = xp0[i * 256]; xfB[i] = xp1[i * 256]; }
  }

  for (int s = 0; s < SS; ++s) {
    int p = s & 1;
    size_t mb = p ? mb1 : mb0;
    const ull* ma = hmb + mb;
    unsigned st = (unsigned)s;
    ull r0, r1, r2, r3;

    // direct agent-scope poll (LLC): 4 independent loads -> one latency/iter
    for (;;) {
      r0 = __hip_atomic_load(ma + lane,        __ATOMIC_RELAXED, __HIP_MEMORY_SCOPE_AGENT);
      r1 = __hip_atomic_load(ma + 64 + lane,   __ATOMIC_RELAXED, __HIP_MEMORY_SCOPE_AGENT);
      r2 = __hip_atomic_load(ma + 128 + lane,  __ATOMIC_RELAXED, __HIP_MEMORY_SCOPE_AGENT);
      r3 = __hip_atomic_load(ma + 192 + lane,  __ATOMIC_RELAXED, __HIP_MEMORY_SCOPE_AGENT);
      unsigned m = (((unsigned)(r0 >> 32)) ^ st) | (((unsigned)(r1 >> 32)) ^ st)
                 | (((unsigned)(r2 >> 32)) ^ st) | (((unsigned)(r3 >> 32)) ^ st);
      if (__all(m == 0u)) break;
    }

    // stage h_s into wave-private LDS (stride-1 across lanes: conflict-free)
    hsh[w][p][lane]       = __uint_as_float((unsigned)r0);
    hsh[w][p][64 + lane]  = __uint_as_float((unsigned)r1);
    hsh[w][p][128 + lane] = __uint_as_float((unsigned)r2);
    hsh[w][p][192 + lane] = __uint_as_float((unsigned)r3);

    // prefetch x-projection for step s+2 (drains at next poll harmlessly)
    float xfN[4] = {0.f, 0.f, 0.f, 0.f};
    if (ul && s + 2 < SS) {
      int tn = dir ? (SS - 3 - s) : (s + 2);
      const float* xp = xsd + (size_t)(tn * BB + b) * G4 + cell;
      #pragma unroll
      for (int i = 0; i < 4; i++) xfN[i] = xp[i * 256];
    }

    asm volatile("s_waitcnt lgkmcnt(0)" ::: "memory");  // own-wave LDS writes done

    // matvec: full 256-k dot, packed f32 FMA; h reads wave-uniform (broadcast)
    f32x4 acc4 = {0.f, 0.f, 0.f, 0.f};
    const float* hb = &hsh[w][p][0];
    #pragma unroll
    for (int j = 0; j < 64; j++) {
      f32x4 hv = *(const f32x4*)(hb + 4 * j);
      acc4 = acc4 + wreg[j] * hv;
    }
    float accv = (acc4.x + acc4.y) + (acc4.z + acc4.w);

    // gather the 4 gate values of this lane's cell (rows g2*16 + cidx)
    float gv[4];
    #pragma unroll
    for (int g2 = 0; g2 < 4; ++g2) gv[g2] = __shfl(accv, g2 * 16 + cidx, 64);

    if (ul) {
      float ig = fsig(gv[0] + xfA[0]);
      float fg = fsig(gv[1] + xfA[1]);
      float gt = ftanh(gv[2] + xfA[2]);
      float og = fsig(gv[3] + xfA[3]);
      cst = fg * cst + ig * gt;
      float hv = og * ftanh(cst);
      ull tagw = ((ull)(unsigned)(s + 1) << 32) | (ull)__float_as_uint(hv);
      size_t mbn = ((s + 1) & 1) ? mb1 : mb0;
      __hip_atomic_store(hmb + mbn + cell, tagw,
                         __ATOMIC_RELAXED, __HIP_MEMORY_SCOPE_AGENT);
      int tcur = dir ? (SS - 1 - s) : s;
      hout[((size_t)(b * SS + tcur)) * 512 + dir * 256 + cell] = hv;
    }

    #pragma unroll
    for (int i = 0; i < 4; i++) { xfA[i] = xfB[i]; xfB[i] = xfN[i]; }
  }
}

// ---------------- emission features ----------------
__global__ void feats_kernel(const float* __restrict__ h1, const float* __restrict__ wout,
                             const float* __restrict__ bout, float* __restrict__ feats) {
  int bs = blockIdx.x;
  int lane = threadIdx.x;
  const float* hp = h1 + (size_t)bs * 512;
  float hv[8];
  #pragma unroll
  for (int i = 0; i < 8; i++) hv[i] = hp[lane + i * 64];
  #pragma unroll
  for (int t = 0; t < TT; t++) {
    const float* wp = wout + t * 512;
    float p = 0.f;
    #pragma unroll
    for (int i = 0; i < 8; i++) p += hv[i] * wp[lane + i * 64];
    #pragma unroll
    for (int off = 32; off >= 1; off >>= 1) p += __shfl_down(p, off, 64);
    if (lane == 0) feats[(size_t)bs * TT + t] = p + bout[t];
  }
}

// ---------------- Viterbi decode ----------------
__global__ void viterbi_kernel(const float* __restrict__ feats, const float* __restrict__ trans,
                               float* __restrict__ out) {
  int b = blockIdx.x;
  int lane = threadIdx.x;
  __shared__ float tr[121];
  __shared__ float fch[32 * TT];
  __shared__ unsigned char bp[SS][12];
  __shared__ unsigned char path[SS];
  for (int i = lane; i < 121; i += 64) tr[i] = trans[i];
  __syncthreads();
  int ln = lane < TT ? lane : (TT - 1);
  float trr[TT];
  #pragma unroll
  for (int p = 0; p < TT; p++) trr[p] = tr[ln * TT + p];
  float fv = (lane == 9) ? 0.f : NEGV;   // START = 9
  const float* fb = feats + (size_t)b * SS * TT;

  for (int s = 0; s < SS; s++) {
    if ((s & 31) == 0) {
      __syncthreads();
      for (int i = lane; i < 32 * TT; i += 64) fch[i] = fb[s * TT + i];
      __syncthreads();
    }
    float best = -3.0e38f; int arg = 0;
    #pragma unroll
    for (int p = 0; p < TT; p++) {
      float v = __shfl(fv, p, 64) + trr[p];
      if (v > best) { best = v; arg = p; }   // strict > keeps FIRST max (numpy argmax)
    }
    if (lane < TT) bp[s][lane] = (unsigned char)arg;
    fv = best + fch[(s & 31) * TT + ln];
  }
  float term = fv + tr[10 * TT + ln];        // STOP = 10
  float best = -3.0e38f; int arg = 0;
  #pragma unroll
  for (int p = 0; p < TT; p++) {
    float v = __shfl(term, p, 64);
    if (v > best) { best = v; arg = p; }
  }
  __syncthreads();
  if (lane == 0) {
    out[b] = best;
    int tg = arg;
    path[SS - 1] = (unsigned char)tg;
    for (int s = SS - 1; s >= 1; s--) {
      tg = bp[s][tg];
      path[s - 1] = (unsigned char)tg;
    }
  }
  __syncthreads();
  for (int i = lane; i < SS; i += 64) out[32 + b * SS + i] = (float)path[i];
}

// ---------------- launcher ----------------
extern "C" void kernel_launch(void* const* d_in, const int* in_sizes, int n_in,
                              void* d_out, int out_size, void* d_ws, size_t ws_size,
                              hipStream_t stream) {
  const int*   x     = (const int*)d_in[0];
  const float* emb   = (const float*)d_in[2];
  const float* wih0f = (const float*)d_in[3];
  const float* whh0f = (const float*)d_in[4];
  const float* b0f   = (const float*)d_in[5];
  const float* wih0b = (const float*)d_in[6];
  const float* whh0b = (const float*)d_in[7];
  const float* b0b   = (const float*)d_in[8];
  const float* wih1f = (const float*)d_in[9];
  const float* whh1f = (const float*)d_in[10];
  const float* b1f   = (const float*)d_in[11];
  const float* wih1b = (const float*)d_in[12];
  const float* whh1b = (const float*)d_in[13];
  const float* b1b   = (const float*)d_in[14];
  const float* wout  = (const float*)d_in[15];
  const float* bout  = (const float*)d_in[16];
  const float* trans = (const float*)d_in[17];

  char* ws = (char*)d_ws;
  unsigned short* xeh = (unsigned short*)(ws + OFF_XEH);
  unsigned short* xel = (unsigned short*)(ws + OFF_XEL);
  float* xs    = (float*)(ws + OFF_XS);
  float* h0    = (float*)(ws + OFF_H0);
  float* h1    = (float*)(ws + OFF_H1);
  unsigned short* h0h = (unsigned short*)(ws + OFF_H1);               // overlay (dead until scan1)
  unsigned short* h0l = (unsigned short*)(ws + OFF_H1 + 16777216ull);
  float* feats = (float*)(ws + OFF_FEATS);
  ull* hmb = (ull*)(ws + OFF_HGRP);
  unsigned short* w0h = (unsigned short*)(ws + OFF_W0H);
  unsigned short* w0l = (unsigned short*)(ws + OFF_W0L);
  unsigned short* w1h = (unsigned short*)(ws + OFF_W1H);
  unsigned short* w1l = (unsigned short*)(ws + OFF_W1L);
  float* outp  = (float*)d_out;

  // embedding gather + hi/lo split
  emb_kernel<<<4096, 256, 0, stream>>>(x, (const float4*)emb, (ushort4*)xeh, (ushort4*)xel);
  // weight splits: wih0 [2][1024][256], wih1 [2][1024][512]
  split_kernel<<<256, 256, 0, stream>>>((const float4*)wih0f, (ushort4*)w0h, (ushort4*)w0l, 65536);
  split_kernel<<<256, 256, 0, stream>>>((const float4*)wih0b, (ushort4*)(w0h + 262144),
                                        (ushort4*)(w0l + 262144), 65536);
  split_kernel<<<512, 256, 0, stream>>>((const float4*)wih1f, (ushort4*)w1h, (ushort4*)w1l, 131072);
  split_kernel<<<512, 256, 0, stream>>>((const float4*)wih1b, (ushort4*)(w1h + 524288),
                                        (ushort4*)(w1l + 524288), 131072);

  proj_mfma<256><<<dim3(256, 8, 2), 256, 0, stream>>>(xeh, xel, w0h, w0l, b0f, b0b, xs);
  hipMemsetAsync(hmb, 0, 262144, stream);   // tag 0 == initial h(0) = 0, both parities
  scan_kernel<<<256, 256, 0, stream>>>(xs, whh0f, whh0b, hmb, h0);

  split_kernel<<<8192, 256, 0, stream>>>((const float4*)h0, (ushort4*)h0h, (ushort4*)h0l, 2097152);
  proj_mfma<512><<<dim3(256, 8, 2), 256, 0, stream>>>(h0h, h0l, w1h, w1l, b1f, b1b, xs);
  hipMemsetAsync(hmb, 0, 262144, stream);
  scan_kernel<<<256, 256, 0, stream>>>(xs, whh1f, whh1b, hmb, h1);

  feats_kernel<<<BB * SS, 64, 0, stream>>>(h1, wout, bout, feats);
  viterbi_kernel<<<BB, 64, 0, stream>>>(feats, trans, outp);
}

// Round 4
// 3003.756 us; speedup vs baseline: 1.9349x; 1.1798x over previous
//
#include <hip/hip_runtime.h>
#include <math.h>

#define SS 512
#define BB 32
#define HH 256
#define G4 1024
#define TT 11
#define NEGV (-1000.0f)

typedef unsigned long long ull;

// ---------------- workspace layout (bytes) ----------------
static const size_t OFF_XEH   = 0;                          // 8,388,608  : xe_hi [16384][256] bf16
static const size_t OFF_XEL   = 8388608ull;                 // 8,388,608  : xe_lo
static const size_t OFF_XS    = 16777216ull;                // 134,217,728: xs [2][S][B][1024] f32
static const size_t OFF_H0    = OFF_XS + 134217728ull;      // 33,554,432 : h1 f32 (scan1 output; h0-f32 no longer exists)
static const size_t OFF_H1    = OFF_H0 + 33554432ull;       // 33,554,432 : h0_hi / h0_lo bf16 (scan0 writes directly)
static const size_t OFF_FEATS = OFF_H1 + 33554432ull;       // 720,896    : feats [B][S][11]
static const size_t OFF_HGRP  = OFF_FEATS + 720896ull;      // 524,288    : fast + slow mailboxes [2][2][32][256] u64 each
static const size_t OFF_W0H   = OFF_HGRP + 1048576ull;      // 1,048,576  : wih0 hi [2][1024][256] bf16
static const size_t OFF_W0L   = OFF_W0H + 1048576ull;       // 1,048,576
static const size_t OFF_W1H   = OFF_W0L + 1048576ull;       // 2,097,152  : wih1 hi [2][1024][512] bf16
static const size_t OFF_W1L   = OFF_W1H + 2097152ull;       // 2,097,152
// total ~226 MB

typedef __attribute__((ext_vector_type(8))) short short8;
typedef __attribute__((ext_vector_type(4))) float f32x4;

// fast transcendentals (1-2 ulp; outputs compared in bf16 w/ large threshold)
__device__ __forceinline__ float fsig(float x) {
  return __builtin_amdgcn_rcpf(1.f + __expf(-x));
}
__device__ __forceinline__ float ftanh(float x) {
  return 1.f - 2.f * __builtin_amdgcn_rcpf(__expf(2.f * x) + 1.f);
}

// raw barrier: drains LDS ops only (NO vmcnt(0) drain)
__device__ __forceinline__ void block_sync_lds() {
  asm volatile("s_waitcnt lgkmcnt(0)\n\ts_barrier" ::: "memory");
}

// ---------------- bf16 hi/lo split helpers ----------------
__device__ __forceinline__ unsigned short bfh(float x) {
  unsigned u = __float_as_uint(x);
  unsigned r = u + 0x7fffu + ((u >> 16) & 1u);   // RNE to bf16 (finite inputs)
  return (unsigned short)(r >> 16);
}
__device__ __forceinline__ void split1(float x, unsigned short& h, unsigned short& l) {
  h = bfh(x);
  float hf = __uint_as_float(((unsigned)h) << 16);
  l = bfh(x - hf);
}

// ---------------- fast-mailbox primitives (same-XCD L2 relay) ----------------
// Plain store leaves a dirty line in the producer CU's XCD-L2 (write-back);
// an sc0 load from a consumer on the SAME XCD reads that L2 directly (~300cy).
// Cross-XCD consumers see a stale tag -> clean miss -> slow path. The tagged
// protocol makes stale lines harmless (tag never matches current step).
__device__ __forceinline__ void fast_load2(const ull* a0, const ull* a1,
                                           ull& r0, ull& r1) {
  asm volatile(
      "global_load_dwordx2 %0, %2, off sc0\n\t"
      "global_load_dwordx2 %1, %3, off sc0\n\t"
      "s_waitcnt vmcnt(0)"
      : "=&v"(r0), "=&v"(r1)
      : "v"(a0), "v"(a1)
      : "memory");
}
__device__ __forceinline__ void fast_store(ull* a, ull v) {
  asm volatile("global_store_dwordx2 %0, %1, off" :: "v"(a), "v"(v) : "memory");
}

// ---------------- embedding gather + split ----------------
__global__ void emb_kernel(const int* __restrict__ x, const float4* __restrict__ emb,
                           ushort4* __restrict__ xeh, ushort4* __restrict__ xel) {
  int idx = blockIdx.x * 256 + threadIdx.x;    // over B*S*64 float4-chunks
  int bs  = idx >> 6;
  int kq  = idx & 63;
  float4 v = emb[(size_t)x[bs] * 64 + kq];
  ushort4 h, l;
  split1(v.x, h.x, l.x); split1(v.y, h.y, l.y);
  split1(v.z, h.z, l.z); split1(v.w, h.w, l.w);
  xeh[idx] = h; xel[idx] = l;
}

// ---------------- generic f32 -> bf16 hi/lo split ----------------
__global__ void split_kernel(const float4* __restrict__ in, ushort4* __restrict__ oh,
                             ushort4* __restrict__ ol, int n4) {
  int i = blockIdx.x * 256 + threadIdx.x;
  if (i < n4) {
    float4 v = in[i];
    ushort4 h, l;
    split1(v.x, h.x, l.x); split1(v.y, h.y, l.y);
    split1(v.z, h.z, l.z); split1(v.w, h.w, l.w);
    oh[i] = h; ol[i] = l;
  }
}

// ---------------- input projection GEMM via split-bf16 MFMA ----------------
// (unchanged -- verified)
template<int K>
__global__ __launch_bounds__(256, 2)
void proj_mfma(const unsigned short* __restrict__ Ah_g, const unsigned short* __restrict__ Al_g,
               const unsigned short* __restrict__ Wh_g, const unsigned short* __restrict__ Wl_g,
               const float* __restrict__ bf, const float* __restrict__ bb,
               float* __restrict__ xs) {
  int tid = threadIdx.x;
  int bm  = blockIdx.x * 64;
  int bn  = blockIdx.y * 128;
  int dir = blockIdx.z;
  const unsigned short* Wh = Wh_g + (size_t)dir * 1024 * K;
  const unsigned short* Wl = Wl_g + (size_t)dir * 1024 * K;
  const float* bias = dir ? bb : bf;
  float* out = xs + (size_t)dir * (SS * BB * G4);

  __shared__ unsigned short AhS[64][40], AlS[64][40];
  __shared__ unsigned short BhS[128][40], BlS[128][40];

  int w = tid >> 6, lane = tid & 63;
  int wm = w >> 1, wn = w & 1;
  int fr = lane & 15, q8 = (lane >> 4) * 8;
  int ra = tid >> 2;
  int ck = (tid & 3) * 8;

  f32x4 acc[2][4];
  #pragma unroll
  for (int mt = 0; mt < 2; mt++)
    #pragma unroll
    for (int nt = 0; nt < 4; nt++) acc[mt][nt] = 0;

  for (int k0 = 0; k0 < K; k0 += 32) {
    __syncthreads();
    *(uint4*)&AhS[ra][ck] = *(const uint4*)(Ah_g + (size_t)(bm + ra) * K + k0 + ck);
    *(uint4*)&AlS[ra][ck] = *(const uint4*)(Al_g + (size_t)(bm + ra) * K + k0 + ck);
    *(uint4*)&BhS[ra][ck]      = *(const uint4*)(Wh + (size_t)(bn + ra) * K + k0 + ck);
    *(uint4*)&BhS[ra + 64][ck] = *(const uint4*)(Wh + (size_t)(bn + ra + 64) * K + k0 + ck);
    *(uint4*)&BlS[ra][ck]      = *(const uint4*)(Wl + (size_t)(bn + ra) * K + k0 + ck);
    *(uint4*)&BlS[ra + 64][ck] = *(const uint4*)(Wl + (size_t)(bn + ra + 64) * K + k0 + ck);
    __syncthreads();

    short8 ah[2], al[2], bh[4], bl[4];
    #pragma unroll
    for (int mt = 0; mt < 2; mt++) {
      ah[mt] = *(const short8*)&AhS[wm * 32 + mt * 16 + fr][q8];
      al[mt] = *(const short8*)&AlS[wm * 32 + mt * 16 + fr][q8];
    }
    #pragma unroll
    for (int nt = 0; nt < 4; nt++) {
      bh[nt] = *(const short8*)&BhS[wn * 64 + nt * 16 + fr][q8];
      bl[nt] = *(const short8*)&BlS[wn * 64 + nt * 16 + fr][q8];
    }
    #pragma unroll
    for (int mt = 0; mt < 2; mt++)
      #pragma unroll
      for (int nt = 0; nt < 4; nt++) {
        acc[mt][nt] = __builtin_amdgcn_mfma_f32_16x16x32_bf16(ah[mt], bh[nt], acc[mt][nt], 0, 0, 0);
        acc[mt][nt] = __builtin_amdgcn_mfma_f32_16x16x32_bf16(ah[mt], bl[nt], acc[mt][nt], 0, 0, 0);
        acc[mt][nt] = __builtin_amdgcn_mfma_f32_16x16x32_bf16(al[mt], bh[nt], acc[mt][nt], 0, 0, 0);
        acc[mt][nt] = __builtin_amdgcn_mfma_f32_16x16x32_bf16(al[mt], bl[nt], acc[mt][nt], 0, 0, 0);
      }
  }

  #pragma unroll
  for (int mt = 0; mt < 2; mt++)
    #pragma unroll
    for (int nt = 0; nt < 4; nt++) {
      int n  = bn + wn * 64 + nt * 16 + fr;
      float bv = bias[n];
      int mbase = bm + wm * 32 + mt * 16 + (lane >> 4) * 4;
      #pragma unroll
      for (int r = 0; r < 4; r++) {
        int mm = mbase + r;
        int b_ = mm >> 9;
        int s_ = mm & 511;
        out[(size_t)(s_ * BB + b_) * G4 + n] = acc[mt][nt][r] + bv;
      }
    }
}

// ---------------- recurrent scan (R12: R9-v2 structure + adaptive same-XCD fast relay) ----------------
// Structure byte-identical to the verified 1247us kernel (grid (8,16,2),
// 4 waves, lane-half k-split, 1 barrier/step, tagged parity mailbox).
// ONLY the transport changed: producers dual-store {fast: plain store,
// slow: agent atomic}; consumers try <=4 sc0 polls on the fast mailbox,
// then fall back to the proven slow poll. A per-wave flag disables the
// fast path permanently if it misses during steps 1..3 (step 0 succeeds
// trivially on the zeroed mailboxes, so it can't probe placement).
// Under chunked XCD dispatch (bid/32), each chain's 8 blocks (bids
// 8*bg+128*dir .. +7, 8-aligned) share one XCD -> fast path works.
// Under round-robin they don't -> adaptive falls back at ~zero cost.
// Correctness is transport-independent: unique tag<->payload binding per
// slot; stale cross-XCD lines never match the expected tag.
template<int BF16OUT>
__global__ __launch_bounds__(256, 1)
void scan_kernel(const float* __restrict__ xs,      // [2][S][B][1024]
                 const float* __restrict__ whhf, const float* __restrict__ whhb,
                 ull* __restrict__ fastM,           // [2][2][32][256] u64
                 ull* __restrict__ slowM,           // [2][2][32][256] u64
                 float* __restrict__ hout,          // [B*S][512] f32 (BF16OUT=0)
                 unsigned short* __restrict__ houth,// [B*S][512] bf16 hi (BF16OUT=1)
                 unsigned short* __restrict__ houtl)
{
  int tid  = threadIdx.x;
  int w    = tid >> 6;          // wave 0..3
  int lane = tid & 63;
  int cg   = blockIdx.x;        // cell group 0..7 (32 cells)
  int bg   = blockIdx.y;        // batch pair 0..15 (2 batches)
  int dir  = blockIdx.z;
  const float* xsd = xs + (size_t)dir * (SS * BB * G4);
  const float* whh = dir ? whhb : whhf;
  size_t dbase = (size_t)dir * 16384;   // [2][32][256] slots per dir

  __shared__ float h_sh[2][2][256];     // [parity][local batch][cell]

  int r    = lane & 31;         // row within wave's 32 rows: gate*8 + cellofs
  int ks   = lane >> 5;         // k-half: 0 -> k<128, 1 -> k>=128
  int g    = r >> 3;            // gate 0..3 (i,f,g,o)
  int c7   = r & 7;
  int cell = cg * 32 + w * 8 + c7;   // global cell of this lane's row
  int grow = g * 256 + cell;         // whh row

  // weights: 1 row x 128 k = 32 float4 in VGPRs
  float4 wreg[32];
  {
    const float* wp = whh + (size_t)grow * 256 + ks * 128;
    #pragma unroll
    for (int j = 0; j < 32; j++) wreg[j] = *(const float4*)(wp + j * 4);
  }

  int b0  = bg * 2;
  int col = tid & 255;          // polled cell column
  bool ul = (r < 8);            // update lane: owns (cell, batch b0+ks)
  int ub  = b0 + ks;
  float cst = 0.f;
  float xf[4];                  // prefetched x-projection (4 gates)
  if (ul) {
    int t0 = dir ? (SS - 1) : 0;
    const float* xp = xsd + (size_t)(t0 * BB + ub) * G4 + cell;
    #pragma unroll
    for (int i = 0; i < 4; i++) xf[i] = xp[i * 256];
  }

  bool use_fast = true;

  for (int s = 0; s < SS; ++s) {
    int p = s & 1;
    size_t mb = dbase + (size_t)(p * 32 + b0) * 256 + col;
    unsigned st = (unsigned)s;
    ull rv0, rv1;
    bool got = false;

    if (use_fast) {
      #pragma unroll 1
      for (int it = 0; it < 4; ++it) {
        fast_load2(fastM + mb, fastM + mb + 256, rv0, rv1);
        unsigned m = (((unsigned)(rv0 >> 32)) ^ st) | (((unsigned)(rv1 >> 32)) ^ st);
        if (__all(m == 0u)) { got = true; break; }
      }
    }
    if (!got) {
      for (;;) {
        rv0 = __hip_atomic_load(slowM + mb,       __ATOMIC_RELAXED, __HIP_MEMORY_SCOPE_AGENT);
        rv1 = __hip_atomic_load(slowM + mb + 256, __ATOMIC_RELAXED, __HIP_MEMORY_SCOPE_AGENT);
        unsigned m = (((unsigned)(rv0 >> 32)) ^ st) | (((unsigned)(rv1 >> 32)) ^ st);
        if (__all(m == 0u)) break;
      }
      if (s >= 1 && s <= 3) use_fast = false;   // placement probe window
    }

    h_sh[p][0][col] = __uint_as_float((unsigned)rv0);
    h_sh[p][1][col] = __uint_as_float((unsigned)rv1);
    block_sync_lds();

    // matvec: 1 row x 2 batches x 128 k per lane (h reads are wave-uniform
    // per half -> LDS broadcast, conflict-free)
    float acc0 = 0.f, acc1 = 0.f;
    const float* hb0 = &h_sh[p][0][ks * 128];
    const float* hb1 = &h_sh[p][1][ks * 128];
    #pragma unroll
    for (int j = 0; j < 32; j++) {
      float4 hv0 = *(const float4*)(hb0 + j * 4);
      float4 hv1 = *(const float4*)(hb1 + j * 4);
      float4 wv  = wreg[j];
      acc0 += wv.x * hv0.x + wv.y * hv0.y + wv.z * hv0.z + wv.w * hv0.w;
      acc1 += wv.x * hv1.x + wv.y * hv1.y + wv.z * hv1.z + wv.w * hv1.w;
    }
    // combine k-halves (lane <-> lane^32 hold same row, complementary k)
    acc0 += __shfl_xor(acc0, 32, 64);
    acc1 += __shfl_xor(acc1, 32, 64);
    // half ks carries batch b0+ks from here on
    float v = ks ? acc1 : acc0;
    // gather the 4 gates of this lane's cell from rows g*8+c in the same half
    float gv[4];
    #pragma unroll
    for (int gg = 0; gg < 4; gg++)
      gv[gg] = __shfl(v, (lane & 32) + gg * 8 + (lane & 7), 64);

    if (ul) {
      float ig = fsig(gv[0] + xf[0]);
      float fg = fsig(gv[1] + xf[1]);
      float gt = ftanh(gv[2] + xf[2]);
      float og = fsig(gv[3] + xf[3]);
      cst = fg * cst + ig * gt;
      float hv = og * ftanh(cst);
      ull tagw = ((ull)(unsigned)(s + 1) << 32) | (ull)__float_as_uint(hv);
      size_t mo = dbase + (size_t)((((s + 1) & 1) * 32 + ub)) * 256 + cell;
      fast_store(fastM + mo, tagw);
      __hip_atomic_store(slowM + mo, tagw,
                         __ATOMIC_RELAXED, __HIP_MEMORY_SCOPE_AGENT);
      int tcur = dir ? (SS - 1 - s) : s;
      size_t hidx = ((size_t)(ub * SS + tcur)) * 512 + dir * 256 + cell;
      if (BF16OUT) {
        unsigned short hh, hl;
        split1(hv, hh, hl);
        houth[hidx] = hh; houtl[hidx] = hl;
      } else {
        hout[hidx] = hv;
      }
      if (s + 1 < SS) {
        int tpn = dir ? (SS - 2 - s) : (s + 1);
        const float* xp = xsd + (size_t)(tpn * BB + ub) * G4 + cell;
        #pragma unroll
        for (int i = 0; i < 4; i++) xf[i] = xp[i * 256];
      }
    }
  }
}

// ---------------- emission features ----------------
__global__ void feats_kernel(const float* __restrict__ h1, const float* __restrict__ wout,
                             const float* __restrict__ bout, float* __restrict__ feats) {
  int bs = blockIdx.x;
  int lane = threadIdx.x;
  const float* hp = h1 + (size_t)bs * 512;
  float hv[8];
  #pragma unroll
  for (int i = 0; i < 8; i++) hv[i] = hp[lane + i * 64];
  #pragma unroll
  for (int t = 0; t < TT; t++) {
    const float* wp = wout + t * 512;
    float p = 0.f;
    #pragma unroll
    for (int i = 0; i < 8; i++) p += hv[i] * wp[lane + i * 64];
    #pragma unroll
    for (int off = 32; off >= 1; off >>= 1) p += __shfl_down(p, off, 64);
    if (lane == 0) feats[(size_t)bs * TT + t] = p + bout[t];
  }
}

// ---------------- Viterbi decode ----------------
__global__ void viterbi_kernel(const float* __restrict__ feats, const float* __restrict__ trans,
                               float* __restrict__ out) {
  int b = blockIdx.x;
  int lane = threadIdx.x;
  __shared__ float tr[121];
  __shared__ float fch[32 * TT];
  __shared__ unsigned char bp[SS][12];
  __shared__ unsigned char path[SS];
  for (int i = lane; i < 121; i += 64) tr[i] = trans[i];
  __syncthreads();
  int ln = lane < TT ? lane : (TT - 1);
  float trr[TT];
  #pragma unroll
  for (int p = 0; p < TT; p++) trr[p] = tr[ln * TT + p];
  float fv = (lane == 9) ? 0.f : NEGV;   // START = 9
  const float* fb = feats + (size_t)b * SS * TT;

  for (int s = 0; s < SS; s++) {
    if ((s & 31) == 0) {
      __syncthreads();
      for (int i = lane; i < 32 * TT; i += 64) fch[i] = fb[s * TT + i];
      __syncthreads();
    }
    float best = -3.0e38f; int arg = 0;
    #pragma unroll
    for (int p = 0; p < TT; p++) {
      float v = __shfl(fv, p, 64) + trr[p];
      if (v > best) { best = v; arg = p; }   // strict > keeps FIRST max (numpy argmax)
    }
    if (lane < TT) bp[s][lane] = (unsigned char)arg;
    fv = best + fch[(s & 31) * TT + ln];
  }
  float term = fv + tr[10 * TT + ln];        // STOP = 10
  float best = -3.0e38f; int arg = 0;
  #pragma unroll
  for (int p = 0; p < TT; p++) {
    float v = __shfl(term, p, 64);
    if (v > best) { best = v; arg = p; }
  }
  __syncthreads();
  if (lane == 0) {
    out[b] = best;
    int tg = arg;
    path[SS - 1] = (unsigned char)tg;
    for (int s = SS - 1; s >= 1; s--) {
      tg = bp[s][tg];
      path[s - 1] = (unsigned char)tg;
    }
  }
  __syncthreads();
  for (int i = lane; i < SS; i += 64) out[32 + b * SS + i] = (float)path[i];
}

// ---------------- launcher ----------------
extern "C" void kernel_launch(void* const* d_in, const int* in_sizes, int n_in,
                              void* d_out, int out_size, void* d_ws, size_t ws_size,
                              hipStream_t stream) {
  const int*   x     = (const int*)d_in[0];
  const float* emb   = (const float*)d_in[2];
  const float* wih0f = (const float*)d_in[3];
  const float* whh0f = (const float*)d_in[4];
  const float* b0f   = (const float*)d_in[5];
  const float* wih0b = (const float*)d_in[6];
  const float* whh0b = (const float*)d_in[7];
  const float* b0b   = (const float*)d_in[8];
  const float* wih1f = (const float*)d_in[9];
  const float* whh1f = (const float*)d_in[10];
  const float* b1f   = (const float*)d_in[11];
  const float* wih1b = (const float*)d_in[12];
  const float* whh1b = (const float*)d_in[13];
  const float* b1b   = (const float*)d_in[14];
  const float* wout  = (const float*)d_in[15];
  const float* bout  = (const float*)d_in[16];
  const float* trans = (const float*)d_in[17];

  char* ws = (char*)d_ws;
  unsigned short* xeh = (unsigned short*)(ws + OFF_XEH);
  unsigned short* xel = (unsigned short*)(ws + OFF_XEL);
  float* xs    = (float*)(ws + OFF_XS);
  float* h1    = (float*)(ws + OFF_H0);                     // scan1 f32 output
  unsigned short* h0h = (unsigned short*)(ws + OFF_H1);     // scan0 bf16 hi
  unsigned short* h0l = (unsigned short*)(ws + OFF_H1 + 16777216ull);
  float* feats = (float*)(ws + OFF_FEATS);
  ull* fastM = (ull*)(ws + OFF_HGRP);
  ull* slowM = (ull*)(ws + OFF_HGRP + 262144ull);
  unsigned short* w0h = (unsigned short*)(ws + OFF_W0H);
  unsigned short* w0l = (unsigned short*)(ws + OFF_W0L);
  unsigned short* w1h = (unsigned short*)(ws + OFF_W1H);
  unsigned short* w1l = (unsigned short*)(ws + OFF_W1L);
  float* outp  = (float*)d_out;

  // embedding gather + hi/lo split
  emb_kernel<<<4096, 256, 0, stream>>>(x, (const float4*)emb, (ushort4*)xeh, (ushort4*)xel);
  // weight splits: wih0 [2][1024][256], wih1 [2][1024][512]
  split_kernel<<<256, 256, 0, stream>>>((const float4*)wih0f, (ushort4*)w0h, (ushort4*)w0l, 65536);
  split_kernel<<<256, 256, 0, stream>>>((const float4*)wih0b, (ushort4*)(w0h + 262144),
                                        (ushort4*)(w0l + 262144), 65536);
  split_kernel<<<512, 256, 0, stream>>>((const float4*)wih1f, (ushort4*)w1h, (ushort4*)w1l, 131072);
  split_kernel<<<512, 256, 0, stream>>>((const float4*)wih1b, (ushort4*)(w1h + 524288),
                                        (ushort4*)(w1l + 524288), 131072);

  proj_mfma<256><<<dim3(256, 8, 2), 256, 0, stream>>>(xeh, xel, w0h, w0l, b0f, b0b, xs);
  hipMemsetAsync(fastM, 0, 524288, stream);   // tag 0 == initial h(0) = 0, both mailboxes
  scan_kernel<1><<<dim3(8, 16, 2), 256, 0, stream>>>(xs, whh0f, whh0b, fastM, slowM,
                                                     nullptr, h0h, h0l);

  proj_mfma<512><<<dim3(256, 8, 2), 256, 0, stream>>>(h0h, h0l, w1h, w1l, b1f, b1b, xs);
  hipMemsetAsync(fastM, 0, 524288, stream);
  scan_kernel<0><<<dim3(8, 16, 2), 256, 0, stream>>>(xs, whh1f, whh1b, fastM, slowM,
                                                     h1, nullptr, nullptr);

  feats_kernel<<<BB * SS, 64, 0, stream>>>(h1, wout, bout, feats);
  viterbi_kernel<<<BB, 64, 0, stream>>>(feats, trans, outp);
}